// Round 14
// baseline (224.437 us; speedup 1.0000x reference)
//
#include <hip/hip_runtime.h>
#include <hip/hip_bf16.h>
#include <math.h>

// Problem constants (fixed shapes from setup_inputs)
#define B_    2
#define N_    2048
#define D_    1024
#define H_    16
#define ENC_  8
#define HD_   64
#define EPS_  1e-5f
#define M_    (B_ * N_)        // 4096 rows for all GEMMs

typedef __bf16 bf16x8 __attribute__((ext_vector_type(8)));
typedef __bf16 bf16x2 __attribute__((ext_vector_type(2)));
typedef float  f32x4  __attribute__((ext_vector_type(4)));

#define MB(x) ((size_t)(x) * 1024 * 1024)

// Softmax scale folded into Q at RoPE time: 0.125 * log2(e)
#define KSC_  0.18033688011112042f

#if __has_builtin(__builtin_amdgcn_exp2f)
#define EXP2F(x) __builtin_amdgcn_exp2f(x)
#else
#define EXP2F(x) exp2f(x)
#endif

// Async global->LDS 16B copy. HW writes lds_base + lane*16 (wave-uniform LDS
// base); the GLOBAL address is per-lane, so scattered gathers are fine.
__device__ __forceinline__ void gld16(const __bf16* g, __bf16* l) {
    __builtin_amdgcn_global_load_lds(
        (const __attribute__((address_space(1))) void*)g,
        (__attribute__((address_space(3))) void*)l,
        16, 0, 0);
}

// ---------------------------------------------------------------------------
// MFMA GEMM core, R14: BK=32 DOUBLE-BUFFER -- prefetch AND occupancy.
// R13 post-mortem: BK=64 dbuf (64KB LDS) washed (-2.5us) because it halved
// occupancy (3 -> 2 blocks/CU): prefetch-ILP gained ~= TLP lost. The A/B
// showed both mechanisms work; BK=32 dbuf gets BOTH: LDS = 2x(8+8) = 32KB
// (same as R11's single-buffered -> occupancy stays at the grid cap) and
// every K-step's stage is issued one full step ahead (no exposed L2 latency,
// one vmcnt(0)+barrier per step via __syncthreads).
// Swizzle is the BK=32 analog of R11's verified involution (rule #21,
// both-sides-or-neither): LINEAR gld16 dest + PRE-SWIZZLED global source
// (chunk cl^(sr&3)) + swizzled ds_read (chunk quad^(lrow&3)). LDS slot
// (row,c) holds global chunk c^(row&3) on both paths. Residual 4-way
// bank conflict (vs 8-way linear), secondary at this structure.
// ---------------------------------------------------------------------------
template <typename OutT>
__device__ __forceinline__ void gemm_core(
    const __bf16* __restrict__ A, const __bf16* __restrict__ Bt,
    OutT* __restrict__ C, int K, int lda, int aoff, int ldc,
    int bm, int bn, __bf16* As, __bf16* Bs)
{
    const int tid  = threadIdx.x;
    const int w    = tid >> 6;
    const int lane = tid & 63;
    const int lrow = lane & 15;
    const int quad = lane >> 4;
    const int wr   = w >> 1;
    const int wc   = w & 1;

    // Staging lane mapping: sr = row-in-16 (lane>>2), cl = 16B chunk (lane&3).
    const int sr = lane >> 2;
    const int cl = lane & 3;
    const int sk = ((cl ^ (sr & 3)) * 8);   // pre-swizzled global k-offset

    const __bf16* Ag0 = A  + (size_t)(bm +      w * 16 + sr) * lda + aoff + sk;
    const __bf16* Ag1 = A  + (size_t)(bm + 64 + w * 16 + sr) * lda + aoff + sk;
    const __bf16* Bg0 = Bt + (size_t)(bn +      w * 16 + sr) * K + sk;
    const __bf16* Bg1 = Bt + (size_t)(bn + 64 + w * 16 + sr) * K + sk;

    f32x4 acc[4][4];
    #pragma unroll
    for (int i = 0; i < 4; ++i)
        #pragma unroll
        for (int j = 0; j < 4; ++j) acc[i][j] = (f32x4){0.f, 0.f, 0.f, 0.f};

    auto stage = [&](int k0, int bb) {
        __bf16* Al = As + bb * 4096 + w * 512;
        __bf16* Bl = Bs + bb * 4096 + w * 512;
        gld16(Ag0 + k0, Al);
        gld16(Ag1 + k0, Al + 2048);
        gld16(Bg0 + k0, Bl);
        gld16(Bg1 + k0, Bl + 2048);
    };

    stage(0, 0);
    __syncthreads();                 // prologue: buf0 ready
    const int ch = (quad ^ (lrow & 3)) * 8;   // swizzled read chunk (inv.)
    int bb = 0;
    for (int k0 = 0; k0 < K; k0 += 32, bb ^= 1) {
        if (k0 + 32 < K) stage(k0 + 32, bb ^ 1);   // prefetch, in flight
        const __bf16* Ab = As + bb * 4096;
        const __bf16* Bb = Bs + bb * 4096;
        bf16x8 af[4], bf[4];
        #pragma unroll
        for (int rt = 0; rt < 4; ++rt)
            af[rt] = *(const bf16x8*)&Ab[(wr * 64 + rt * 16 + lrow) * 32 + ch];
        #pragma unroll
        for (int ct = 0; ct < 4; ++ct)
            bf[ct] = *(const bf16x8*)&Bb[(wc * 64 + ct * 16 + lrow) * 32 + ch];

        #pragma unroll
        for (int rt = 0; rt < 4; ++rt)
            #pragma unroll
            for (int ct = 0; ct < 4; ++ct)
                acc[rt][ct] = __builtin_amdgcn_mfma_f32_16x16x32_bf16(
                    af[rt], bf[ct], acc[rt][ct], 0, 0, 0);
        __syncthreads();             // drains prefetch; protects buf reuse
    }

    #pragma unroll
    for (int rt = 0; rt < 4; ++rt)
        #pragma unroll
        for (int ct = 0; ct < 4; ++ct)
            #pragma unroll
            for (int r = 0; r < 4; ++r) {
                const int row = bm + wr * 64 + rt * 16 + quad * 4 + r;
                const int col = bn + wc * 64 + ct * 16 + lrow;
                C[(size_t)row * ldc + col] = (OutT)acc[rt][ct][r];
            }
}

// QKV projection GEMM (bf16 out)
__global__ __launch_bounds__(256) void gemm_qkv(
    const __bf16* __restrict__ A, const __bf16* __restrict__ Bt,
    __bf16* __restrict__ C)
{
    __shared__ __bf16 As[2 * 128 * 32];
    __shared__ __bf16 Bs[2 * 128 * 32];
    gemm_core<__bf16>(A, Bt, C, D_, D_, 0, 3072,
                      blockIdx.y * 128, blockIdx.x * 128, As, Bs);
}

// Merged output projections: balanced 1-D grid of 512 (R11): id<256 = enc
// (K=1024), id>=256 = dec (K=512) -> each CU gets one of each.
__global__ __launch_bounds__(256) void gemm_out(
    const __bf16* __restrict__ A, const __bf16* __restrict__ Woe,
    const __bf16* __restrict__ Wod, float* __restrict__ Cenc,
    float* __restrict__ Cdec)
{
    __shared__ __bf16 As[2 * 128 * 32];
    __shared__ __bf16 Bs[2 * 128 * 32];
    const int id = blockIdx.x;
    if (id < 256) {
        gemm_core<float>(A, Woe, Cenc, 1024, D_, 0, D_,
                         (id >> 3) * 128, (id & 7) * 128, As, Bs);
    } else {
        const int idx = id - 256;
        gemm_core<float>(A, Wod, Cdec, 512, D_, 512, D_,
                         (idx >> 3) * 128, (idx & 7) * 128, As, Bs);
    }
}

// ---------------------------------------------------------------------------
// All 5 weight converts (fp32 W[K][Nn] -> bf16 Wt[Nn][K]) AND the x f32->bf16
// convert in ONE launch (saves a serial kernel launch).
// grid (16, 16, 13): z<5 = weight transpose-converts (z=4 uses only y<8);
// z in [5,13) = x convert, linear chunk = (z-5)*256 + y*16 + x  (2048 chunks
// x 2048 elems = 4096x1024).
// ---------------------------------------------------------------------------
struct WtArgs {
    const float* W[5];
    __bf16*      Wt[5];
    int          K[5];      // rows of W == inner stride of Wt
    int          nyb[5];    // grid-y blocks used
    const float* x;
    __bf16*      xbf;
};

__global__ __launch_bounds__(256) void wt_conv_all(WtArgs ar)
{
    const int z = blockIdx.z;
    if (z >= 5) {
        const int linear = (z - 5) * 256 + blockIdx.y * 16 + blockIdx.x;
        const size_t i = ((size_t)linear * 256 + threadIdx.x) * 8;
        float4 a = *(const float4*)&ar.x[i];
        float4 b = *(const float4*)&ar.x[i + 4];
        bf16x8 o = {(__bf16)a.x, (__bf16)a.y, (__bf16)a.z, (__bf16)a.w,
                    (__bf16)b.x, (__bf16)b.y, (__bf16)b.z, (__bf16)b.w};
        *(bf16x8*)&ar.xbf[i] = o;
        return;
    }
    if (blockIdx.y >= ar.nyb[z]) return;
    const float* W  = ar.W[z];
    __bf16*      Wt = ar.Wt[z];
    const int    K  = ar.K[z];

    __shared__ __bf16 t[64][72];
    const int kb = blockIdx.y * 64;
    const int nb = blockIdx.x * 64;
    {
        const int kl = threadIdx.x >> 2;
        const int c0 = (threadIdx.x & 3) * 16;
        const float* src = W + (size_t)(kb + kl) * D_ + nb + c0;
        #pragma unroll
        for (int u = 0; u < 4; ++u) {
            float4 f = *(const float4*)&src[u * 4];
            t[c0 + u * 4 + 0][kl] = (__bf16)f.x;
            t[c0 + u * 4 + 1][kl] = (__bf16)f.y;
            t[c0 + u * 4 + 2][kl] = (__bf16)f.z;
            t[c0 + u * 4 + 3][kl] = (__bf16)f.w;
        }
    }
    __syncthreads();
    {
        const int nl  = threadIdx.x >> 2;
        const int k0c = (threadIdx.x & 3) * 16;
        __bf16* dst = Wt + (size_t)(nb + nl) * K + kb + k0c;
        *(bf16x8*)&dst[0] = *(const bf16x8*)&t[nl][k0c];
        *(bf16x8*)&dst[8] = *(const bf16x8*)&t[nl][k0c + 8];
    }
}

// ---------------------------------------------------------------------------
// Fused RoPE+RMSNorm (q,k) + V transpose, one launch.
// blocks [0,16384): rope path (4 rows/block); [16384,17408): vconv path.
// Q is pre-scaled by 0.125*log2e (softmax scale folded in).
// V^T key permutation for IN-REGISTER P (swapped QK^T):
//   pos = quad*8 + hi*4 + lo  <->  key = hi*16 + quad*4 + lo
//   (pos within each 32-key group; quad=(pos>>3)&3, hi=(pos>>2)&1, lo=pos&3)
// With S^T = mfma(K,Q), lane (quad,lrow) holds P[key=jp+{hi*16+quad*4+r}]
// [q=i0+lrow] in s0/s1 regs -> its PV A-fragment IS {s0[0..3],s1[0..3]}
// under this V key order. No P LDS round-trip.
// ---------------------------------------------------------------------------
__global__ __launch_bounds__(256) void rope_vconv(
    const __bf16* __restrict__ qkv,
    const float* __restrict__ cs, const float* __restrict__ sn,
    __bf16* __restrict__ qbf, __bf16* __restrict__ kbf,
    __bf16* __restrict__ vt)
{
    if (blockIdx.x < 16384) {
        const int row  = blockIdx.x * 4 + (threadIdx.x >> 6);  // (b*N+n)*H + h
        const int lane = threadIdx.x & 63;
        const int n    = (row >> 4) & (N_ - 1);
        const int b    = row >> 15;
        const int h    = row & 15;
        const int p    = lane >> 1;

        const float c = cs[n * (HD_ / 2) + p];
        const float s = sn[n * (HD_ / 2) + p];
        const size_t ibase = (size_t)(b * N_ + n) * 3072 + h * HD_ + lane;
        const size_t obase = ((size_t)(b * H_ + h) * N_ + n) * HD_ + lane;
        const bool odd = (lane & 1);

        {
            float val = (float)qkv[ibase];                  // q
            float partner = __shfl_xor(val, 1, 64);
            float r = odd ? fmaf(partner, s, val * c)
                          : (val * c - partner * s);
            float ss = r * r;
            #pragma unroll
            for (int off = 1; off < 64; off <<= 1) ss += __shfl_xor(ss, off, 64);
            qbf[obase] = (__bf16)(r * rsqrtf(ss * (1.0f / 64.0f) + EPS_) * KSC_);
        }
        {
            float val = (float)qkv[ibase + 1024];           // k
            float partner = __shfl_xor(val, 1, 64);
            float r = odd ? fmaf(partner, s, val * c)
                          : (val * c - partner * s);
            float ss = r * r;
            #pragma unroll
            for (int off = 1; off < 64; off <<= 1) ss += __shfl_xor(ss, off, 64);
            kbf[obase] = (__bf16)(r * rsqrtf(ss * (1.0f / 64.0f) + EPS_));
        }
    } else {
        __shared__ __bf16 tile[64][72];
        const int bx = blockIdx.x - 16384;
        const int bh = bx >> 5;
        const int b  = bh >> 4, h = bh & 15;
        const int n0 = (bx & 31) * 64;
        {
            const int nl = threadIdx.x >> 2;
            const int d0 = (threadIdx.x & 3) * 16;
            const __bf16* src =
                qkv + (size_t)(b * N_ + n0 + nl) * 3072 + 2048 + h * HD_ + d0;
            bf16x8 v0 = *(const bf16x8*)&src[0];
            bf16x8 v1 = *(const bf16x8*)&src[8];
            #pragma unroll
            for (int e = 0; e < 8; ++e) {
                tile[d0 + e][nl]     = v0[e];
                tile[d0 + 8 + e][nl] = v1[e];
            }
        }
        __syncthreads();
        {
            const int dl = threadIdx.x >> 2;
            const int nc = (threadIdx.x & 3) * 16;
            __bf16* dst = vt + ((size_t)(bh * HD_ + dl)) * N_ + n0 + nc;
            bf16x8 o0, o1;
            // dst position p holds original key inv(p):
            //   inv(p) = ((p>>2)&1)*16 + ((p>>3)&3)*4 + (p&3)  (within 32-grp)
            #pragma unroll
            for (int e = 0; e < 8; ++e) {
                const int p0 = nc + e;
                const int p1 = nc + 8 + e;
                o0[e] = tile[dl][(p0 & ~31) + (((p0 >> 2) & 1) << 4)
                                 + (((p0 >> 3) & 3) << 2) + (p0 & 3)];
                o1[e] = tile[dl][(p1 & ~31) + (((p1 >> 2) & 1) << 4)
                                 + (((p1 >> 3) & 3) << 2) + (p1 & 3)];
            }
            *(bf16x8*)&dst[0] = o0;
            *(bf16x8*)&dst[8] = o1;
        }
    }
}

// ---------------------------------------------------------------------------
// MFMA flash attention v15 (bf16 in, bf16 out) — UNCHANGED (53.5us floor;
// merged-pass null showed the compiler already interleaves).
// NO setprio (R17/R18 A/B: -23% in our barrier-synced multi-block regime).
// In-register P via swapped QK^T; LDS = K/V only (32.8 KB).
//   K LDS: chunk p = dimchunk*64 + key   (8 dc x 64 keys)
//   V LDS: chunk p = keyoct*64 + dim     (8 ko x 64 dims)  [keys permuted]
// Grid 768 = 3/CU: 256 enc (NG=2) + 512 dec (NG=1, complementary order).
// XCD-keyed: id%8 = head slot (2 enc bh + 2 dec bh per XCD -> 2 MB in L2).
// ---------------------------------------------------------------------------
template <int NG, bool DEC>
__device__ __forceinline__ void attn_core(
    const __bf16* __restrict__ qbase, const __bf16* __restrict__ kbase,
    const __bf16* __restrict__ vbase, __bf16* __restrict__ o,
    int b, int h, int qb, int ntiles,
    __bf16 (*Ks)[4096], __bf16 (*Vs)[4096])
{
    const int tid  = threadIdx.x;
    const int w    = tid >> 6;
    const int lane = tid & 63;
    const int lrow = lane & 15;
    const int quad = lane >> 4;

    // Staging (wave w handles chunk groups m = w and m = w+4):
    //   K group m: lane l -> key l, dims [m*8, m*8+8)
    //   V group m: lane l -> dim l, keypos [m*8, m*8+8)
    const __bf16* kg0 = kbase + (size_t)lane * HD_ + w * 8;        // m=w
    const __bf16* kg1 = kbase + (size_t)lane * HD_ + (w + 4) * 8;  // m=w+4
    const __bf16* vg  = vbase + (size_t)lane * N_;

    // Wave w, group g covers q-rows [i0g, i0g+16)
    int i0g[NG];
    #pragma unroll
    for (int g = 0; g < NG; ++g) i0g[g] = qb * (NG * 64) + g * 64 + w * 16;

    bf16x8 qf[NG][2];
    #pragma unroll
    for (int g = 0; g < NG; ++g)
        #pragma unroll
        for (int kc = 0; kc < 2; ++kc)
            qf[g][kc] = *(const bf16x8*)
                &qbase[(size_t)(i0g[g] + lrow) * HD_ + kc * 32 + quad * 8];

    const f32x4 zero = {0.f, 0.f, 0.f, 0.f};
    f32x4 oacc[NG][4];
    float lsum[NG];
    #pragma unroll
    for (int g = 0; g < NG; ++g) {
        lsum[g] = 0.f;
        #pragma unroll
        for (int c = 0; c < 4; ++c) oacc[g][c] = zero;
    }

    auto stage = [&](int t, int bb) {
        const int j0 = t << 6;
        gld16(kg0 + (size_t)j0 * HD_, &Ks[bb][(w)     * 512]);
        gld16(kg1 + (size_t)j0 * HD_, &Ks[bb][(w + 4) * 512]);
        gld16(vg + j0 + w * 8,        &Vs[bb][(w)     * 512]);
        gld16(vg + j0 + (w + 4) * 8,  &Vs[bb][(w + 4) * 512]);
    };

    stage(0, 0);
    for (int t = 0; t < ntiles; ++t) {
        const int bb = t & 1;
        __syncthreads();            // buf bb staged; prev compute done
        if (t + 1 < ntiles) stage(t + 1, bb ^ 1);

        const int j64 = t << 6;
        // dec: pass 1 (keys [j64+32, j64+64)) entirely above the diagonal
        // for this wave's rows? (wave-uniform -> cheap s_cbranch skip)
        const bool do1 = !DEC || (j64 + 32 <= i0g[0] + 15);

        bf16x8 pf[2][NG];

        // ---- QK + softmax, pass 0 (keys [j64, j64+32)) ----
        {
            bf16x8 kf0 = *(const bf16x8*)&Ks[bb][((quad)     * 64 + lrow) * 8];
            bf16x8 kf1 = *(const bf16x8*)&Ks[bb][((4 + quad) * 64 + lrow) * 8];
            bf16x8 kf2 = *(const bf16x8*)&Ks[bb][((quad)     * 64 + 16 + lrow) * 8];
            bf16x8 kf3 = *(const bf16x8*)&Ks[bb][((4 + quad) * 64 + 16 + lrow) * 8];

            f32x4 s0[NG], s1[NG];
            #pragma unroll
            for (int g = 0; g < NG; ++g) { s0[g] = zero; s1[g] = zero; }
            #pragma unroll
            for (int g = 0; g < NG; ++g)
                s0[g] = __builtin_amdgcn_mfma_f32_16x16x32_bf16(kf0, qf[g][0], s0[g], 0, 0, 0);
            #pragma unroll
            for (int g = 0; g < NG; ++g)
                s0[g] = __builtin_amdgcn_mfma_f32_16x16x32_bf16(kf1, qf[g][1], s0[g], 0, 0, 0);
            #pragma unroll
            for (int g = 0; g < NG; ++g)
                s1[g] = __builtin_amdgcn_mfma_f32_16x16x32_bf16(kf2, qf[g][0], s1[g], 0, 0, 0);
            #pragma unroll
            for (int g = 0; g < NG; ++g)
                s1[g] = __builtin_amdgcn_mfma_f32_16x16x32_bf16(kf3, qf[g][1], s1[g], 0, 0, 0);

            #pragma unroll
            for (int g = 0; g < NG; ++g) {
                float pA[4], pB[4];
                if (DEC && (j64 + 31 > i0g[g])) {   // pass reaches diagonal
                    const int i = i0g[g] + lrow;
                    #pragma unroll
                    for (int r = 0; r < 4; ++r) {
                        const int k0 = j64 + quad * 4 + r;
                        pA[r] = (k0      <= i) ? EXP2F(s0[g][r]) : 0.f;
                        pB[r] = (k0 + 16 <= i) ? EXP2F(s1[g][r]) : 0.f;
                    }
                } else {
                    #pragma unroll
                    for (int r = 0; r < 4; ++r) {
                        pA[r] = EXP2F(s0[g][r]);
                        pB[r] = EXP2F(s1[g][r]);
                    }
                }
                lsum[g] += (pA[0] + pA[1]) + (pA[2] + pA[3])
                         + (pB[0] + pB[1]) + (pB[2] + pB[3]);
                pf[0][g] = (bf16x8){(__bf16)pA[0], (__bf16)pA[1],
                                    (__bf16)pA[2], (__bf16)pA[3],
                                    (__bf16)pB[0], (__bf16)pB[1],
                                    (__bf16)pB[2], (__bf16)pB[3]};
            }
        }

        // ---- QK + softmax, pass 1 (keys [j64+32, j64+64)) ----
        if (do1) {
            bf16x8 kf0 = *(const bf16x8*)&Ks[bb][((quad)     * 64 + 32 + lrow) * 8];
            bf16x8 kf1 = *(const bf16x8*)&Ks[bb][((4 + quad) * 64 + 32 + lrow) * 8];
            bf16x8 kf2 = *(const bf16x8*)&Ks[bb][((quad)     * 64 + 48 + lrow) * 8];
            bf16x8 kf3 = *(const bf16x8*)&Ks[bb][((4 + quad) * 64 + 48 + lrow) * 8];

            f32x4 s0[NG], s1[NG];
            #pragma unroll
            for (int g = 0; g < NG; ++g) { s0[g] = zero; s1[g] = zero; }
            #pragma unroll
            for (int g = 0; g < NG; ++g)
                s0[g] = __builtin_amdgcn_mfma_f32_16x16x32_bf16(kf0, qf[g][0], s0[g], 0, 0, 0);
            #pragma unroll
            for (int g = 0; g < NG; ++g)
                s0[g] = __builtin_amdgcn_mfma_f32_16x16x32_bf16(kf1, qf[g][1], s0[g], 0, 0, 0);
            #pragma unroll
            for (int g = 0; g < NG; ++g)
                s1[g] = __builtin_amdgcn_mfma_f32_16x16x32_bf16(kf2, qf[g][0], s1[g], 0, 0, 0);
            #pragma unroll
            for (int g = 0; g < NG; ++g)
                s1[g] = __builtin_amdgcn_mfma_f32_16x16x32_bf16(kf3, qf[g][1], s1[g], 0, 0, 0);

            const int jp = j64 + 32;
            #pragma unroll
            for (int g = 0; g < NG; ++g) {
                float pA[4], pB[4];
                if (DEC && (jp + 31 > i0g[g])) {   // pass reaches diagonal
                    const int i = i0g[g] + lrow;
                    #pragma unroll
                    for (int r = 0; r < 4; ++r) {
                        const int k0 = jp + quad * 4 + r;
                        pA[r] = (k0      <= i) ? EXP2F(s0[g][r]) : 0.f;
                        pB[r] = (k0 + 16 <= i) ? EXP2F(s1[g][r]) : 0.f;
                    }
                } else {
                    #pragma unroll
                    for (int r = 0; r < 4; ++r) {
                        pA[r] = EXP2F(s0[g][r]);
                        pB[r] = EXP2F(s1[g][r]);
                    }
                }
                lsum[g] += (pA[0] + pA[1]) + (pA[2] + pA[3])
                         + (pB[0] + pB[1]) + (pB[2] + pB[3]);
                pf[1][g] = (bf16x8){(__bf16)pA[0], (__bf16)pA[1],
                                    (__bf16)pA[2], (__bf16)pA[3],
                                    (__bf16)pB[0], (__bf16)pB[1],
                                    (__bf16)pB[2], (__bf16)pB[3]};
            }
        }

        // ---- PV, pass 0 ----
        {
            bf16x8 vf0 = *(const bf16x8*)&Vs[bb][((quad) * 64 +  0 + lrow) * 8];
            bf16x8 vf1 = *(const bf16x8*)&Vs[bb][((quad) * 64 + 16 + lrow) * 8];
            bf16x8 vf2 = *(const bf16x8*)&Vs[bb][((quad) * 64 + 32 + lrow) * 8];
            bf16x8 vf3 = *(const bf16x8*)&Vs[bb][((quad) * 64 + 48 + lrow) * 8];
            #pragma unroll
            for (int g = 0; g < NG; ++g) {
                oacc[g][0] = __builtin_amdgcn_mfma_f32_16x16x32_bf16(pf[0][g], vf0, oacc[g][0], 0, 0, 0);
                oacc[g][1] = __builtin_amdgcn_mfma_f32_16x16x32_bf16(pf[0][g], vf1, oacc[g][1], 0, 0, 0);
                oacc[g][2] = __builtin_amdgcn_mfma_f32_16x16x32_bf16(pf[0][g], vf2, oacc[g][2], 0, 0, 0);
                oacc[g][3] = __builtin_amdgcn_mfma_f32_16x16x32_bf16(pf[0][g], vf3, oacc[g][3], 0, 0, 0);
            }
        }

        // ---- PV, pass 1 ----
        if (do1) {
            bf16x8 vf0 = *(const bf16x8*)&Vs[bb][((4 + quad) * 64 +  0 + lrow) * 8];
            bf16x8 vf1 = *(const bf16x8*)&Vs[bb][((4 + quad) * 64 + 16 + lrow) * 8];
            bf16x8 vf2 = *(const bf16x8*)&Vs[bb][((4 + quad) * 64 + 32 + lrow) * 8];
            bf16x8 vf3 = *(const bf16x8*)&Vs[bb][((4 + quad) * 64 + 48 + lrow) * 8];
            #pragma unroll
            for (int g = 0; g < NG; ++g) {
                oacc[g][0] = __builtin_amdgcn_mfma_f32_16x16x32_bf16(pf[1][g], vf0, oacc[g][0], 0, 0, 0);
                oacc[g][1] = __builtin_amdgcn_mfma_f32_16x16x32_bf16(pf[1][g], vf1, oacc[g][1], 0, 0, 0);
                oacc[g][2] = __builtin_amdgcn_mfma_f32_16x16x32_bf16(pf[1][g], vf2, oacc[g][2], 0, 0, 0);
                oacc[g][3] = __builtin_amdgcn_mfma_f32_16x16x32_bf16(pf[1][g], vf3, oacc[g][3], 0, 0, 0);
            }
        }
    }

    // Row sums: lane holds partial for q=lrow over its quad's keys.
    // Combine quads (lanes lrow, 16+lrow, 32+lrow, 48+lrow), then gather
    // the recip for q = quad*4+r from lane (quad*4+r).
    float lrec[NG][4];
    #pragma unroll
    for (int g = 0; g < NG; ++g) {
        float s = lsum[g];
        s += __shfl_xor(s, 16, 64);
        s += __shfl_xor(s, 32, 64);
        s = 1.0f / s;
        #pragma unroll
        for (int r = 0; r < 4; ++r)
            lrec[g][r] = __shfl(s, quad * 4 + r, 64);
    }

    // O (bf16, [4096][1024], col = h*64 + dim); C-layout row=q=quad*4+r
    #pragma unroll
    for (int g = 0; g < NG; ++g)
        #pragma unroll
        for (int c = 0; c < 4; ++c)
            #pragma unroll
            for (int r = 0; r < 4; ++r) {
                const int i = i0g[g] + quad * 4 + r;
                o[(size_t)(b * N_ + i) * D_ + h * HD_ + c * 16 + lrow] =
                    (__bf16)(oacc[g][c][r] * lrec[g][r]);
            }
}

__global__ __launch_bounds__(256) void attn_mfma(
    const __bf16* __restrict__ qbf, const __bf16* __restrict__ kbf,
    const __bf16* __restrict__ vtbf, __bf16* __restrict__ o)
{
    __shared__ __bf16 Ks[2][4096];       // 8 KB per buffer
    __shared__ __bf16 Vs[2][4096];

    if (blockIdx.x < 256) {
        // enc: id = qb*16 + e  (XCD = e%8); 128-row blocks, NG=2
        const int e  = blockIdx.x & 15;
        const int bh = (e >> 3) * 16 + (e & 7);
        const int qb = blockIdx.x >> 4;          // 0..15
        attn_core<2, false>(
            qbf  + (size_t)bh * N_ * HD_, kbf + (size_t)bh * N_ * HD_,
            vtbf + (size_t)bh * HD_ * N_, o,
            bh >> 4, bh & 15, qb, N_ >> 6, Ks, Vs);
    } else {
        // dec: id = 256 + p*16 + d (XCD = d%8); 64-row blocks.
        // Complementary qb order (p<16 -> 31-p heavy, else p-16): the two
        // dec blocks landing on one CU sum to 33 tiles; per-CU makespan is
        // governed by the 32-tile enc block either way.
        const int idx = blockIdx.x - 256;
        const int d   = idx & 15;
        const int bh  = (d >> 3) * 16 + 8 + (d & 7);
        const int p   = idx >> 4;                // 0..31
        const int qb  = (p < 16) ? (31 - p) : (p - 16);
        attn_core<1, true>(
            qbf  + (size_t)bh * N_ * HD_, kbf + (size_t)bh * N_ * HD_,
            vtbf + (size_t)bh * HD_ * N_, o,
            bh >> 4, bh & 15, qb, qb + 1, Ks, Vs);
    }
}

// ---------------------------------------------------------------------------
extern "C" void kernel_launch(void* const* d_in, const int* in_sizes, int n_in,
                              void* d_out, int out_size, void* d_ws, size_t ws_size,
                              hipStream_t stream)
{
    const float* x   = (const float*)d_in[0];
    const float* cs  = (const float*)d_in[1];
    const float* sn  = (const float*)d_in[2];
    const float* Wq  = (const float*)d_in[3];
    const float* Wk  = (const float*)d_in[4];
    const float* Wv  = (const float*)d_in[5];
    const float* Woe = (const float*)d_in[6];
    const float* Wod = (const float*)d_in[7];

    float* enc_out = (float*)d_out;
    float* dec_out = enc_out + (size_t)M_ * D_;

    // Workspace (57 MB), stream-ordered aliasing:
    //   [0,8)    xbf      -> reused as vtbf after QKV GEMM
    //   [8,14)   wqkv_t   (3072 x 1024 bf16)
    //   [14,16)  woe_t    (1024 x 1024 bf16)
    //   [16,17)  wod_t    (1024 x 512 bf16)
    //   [17,41)  qkv      (4096 x 3072 bf16) -> reused as obuf
    //   [41,49)  qbf head-major
    //   [49,57)  kbf head-major
    char* ws = (char*)d_ws;
    __bf16* xbf    = (__bf16*)(ws);
    __bf16* wqkv_t = (__bf16*)(ws + MB(8));
    __bf16* woe_t  = (__bf16*)(ws + MB(14));
    __bf16* wod_t  = (__bf16*)(ws + MB(16));
    __bf16* qkv    = (__bf16*)(ws + MB(17));
    __bf16* qbf    = (__bf16*)(ws + MB(41));
    __bf16* kbf    = (__bf16*)(ws + MB(49));
    __bf16* vtbf   = xbf;     // xbf dead after QKV GEMM
    __bf16* obuf   = qkv;     // qkv dead after rope_vconv

    // All weight converts + x convert in one launch
    WtArgs wa;
    wa.W[0] = Wq;  wa.Wt[0] = wqkv_t;                 wa.K[0] = 1024; wa.nyb[0] = 16;
    wa.W[1] = Wk;  wa.Wt[1] = wqkv_t + 1024 * 1024;   wa.K[1] = 1024; wa.nyb[1] = 16;
    wa.W[2] = Wv;  wa.Wt[2] = wqkv_t + 2048 * 1024;   wa.K[2] = 1024; wa.nyb[2] = 16;
    wa.W[3] = Woe; wa.Wt[3] = woe_t;                  wa.K[3] = 1024; wa.nyb[3] = 16;
    wa.W[4] = Wod; wa.Wt[4] = wod_t;                  wa.K[4] = 512;  wa.nyb[4] = 8;
    wa.x = x; wa.xbf = xbf;
    wt_conv_all<<<dim3(16, 16, 13), 256, 0, stream>>>(wa);

    // Fused QKV projection (bf16 out)
    gemm_qkv<<<dim3(3072 / 128, M_ / 128), 256, 0, stream>>>(xbf, wqkv_t, qkv);

    // RoPE+RMSNorm (Q pre-scaled) + V transpose (key-permuted), one launch
    rope_vconv<<<16384 + 1024, 256, 0, stream>>>(qkv, cs, sn, qbf, kbf, vtbf);

    // Attention: 768 blocks = 3/CU (256 enc NG=2 + 512 dec complementary)
    attn_mfma<<<dim3(768), 256, 0, stream>>>(qbf, kbf, vtbf, obuf);

    // Merged output projections (fp32 out), balanced 1-D grid
    gemm_out<<<dim3(512), 256, 0, stream>>>(
        obuf, woe_t, wod_t, enc_out, dec_out);
}

// Round 17
// 209.429 us; speedup vs baseline: 1.0717x; 1.0717x over previous
//
#include <hip/hip_runtime.h>
#include <hip/hip_bf16.h>
#include <math.h>

// Problem constants (fixed shapes from setup_inputs)
#define B_    2
#define N_    2048
#define D_    1024
#define H_    16
#define ENC_  8
#define HD_   64
#define EPS_  1e-5f
#define M_    (B_ * N_)        // 4096 rows for all GEMMs

typedef __bf16 bf16x8 __attribute__((ext_vector_type(8)));
typedef __bf16 bf16x2 __attribute__((ext_vector_type(2)));
typedef float  f32x4  __attribute__((ext_vector_type(4)));

#define MB(x) ((size_t)(x) * 1024 * 1024)

// Softmax scale folded into Q at RoPE time: 0.125 * log2(e)
#define KSC_  0.18033688011112042f

#if __has_builtin(__builtin_amdgcn_exp2f)
#define EXP2F(x) __builtin_amdgcn_exp2f(x)
#else
#define EXP2F(x) exp2f(x)
#endif

// Async global->LDS 16B copy. HW writes lds_base + lane*16 (wave-uniform LDS
// base); the GLOBAL address is per-lane, so scattered gathers are fine.
__device__ __forceinline__ void gld16(const __bf16* g, __bf16* l) {
    __builtin_amdgcn_global_load_lds(
        (const __attribute__((address_space(1))) void*)g,
        (__attribute__((address_space(3))) void*)l,
        16, 0, 0);
}

// ---------------------------------------------------------------------------
// MFMA GEMM core — R13's exact BK=64 DOUBLE-BUFFER (best measured: 217.6us;
// R14's BK=32 dbuf regressed +7us: more barriers, less compute per stage
// window). Double-buffered prefetch: STAGE(t+1) issued before compute(t),
// one vmcnt(0)+barrier per K-step. LDS = 2x32KB = 64KB (2 blocks/CU).
// BK=64 + XOR swizzle (rule #21 both-sides-or-neither): LINEAR gld16 dest +
// PRE-SWIZZLED global source (k-chunk cl^sr) + swizzled ds_read (chunk
// (h*4+quad)^(lrow&7)) -> conflict-free fragment reads.
// ---------------------------------------------------------------------------
template <typename OutT>
__device__ __forceinline__ void gemm_core(
    const __bf16* __restrict__ A, const __bf16* __restrict__ Bt,
    OutT* __restrict__ C, int K, int lda, int aoff, int ldc,
    int bm, int bn, __bf16* As, __bf16* Bs)
{
    const int tid  = threadIdx.x;
    const int w    = tid >> 6;
    const int lane = tid & 63;
    const int lrow = lane & 15;
    const int quad = lane >> 4;
    const int wr   = w >> 1;
    const int wc   = w & 1;

    // Staging lane mapping: sr = row-in-8 (lane>>3), cl = 16B chunk (lane&7).
    const int sr = lane >> 3;
    const int cl = lane & 7;
    const int sk = ((cl ^ sr) * 8);

    const __bf16* Ag0 = A  + (size_t)(bm +  0 + w * 8 + sr) * lda + aoff + sk;
    const __bf16* Ag1 = A  + (size_t)(bm + 32 + w * 8 + sr) * lda + aoff + sk;
    const __bf16* Ag2 = A  + (size_t)(bm + 64 + w * 8 + sr) * lda + aoff + sk;
    const __bf16* Ag3 = A  + (size_t)(bm + 96 + w * 8 + sr) * lda + aoff + sk;
    const __bf16* Bg0 = Bt + (size_t)(bn +  0 + w * 8 + sr) * K + sk;
    const __bf16* Bg1 = Bt + (size_t)(bn + 32 + w * 8 + sr) * K + sk;
    const __bf16* Bg2 = Bt + (size_t)(bn + 64 + w * 8 + sr) * K + sk;
    const __bf16* Bg3 = Bt + (size_t)(bn + 96 + w * 8 + sr) * K + sk;

    f32x4 acc[4][4];
    #pragma unroll
    for (int i = 0; i < 4; ++i)
        #pragma unroll
        for (int j = 0; j < 4; ++j) acc[i][j] = (f32x4){0.f, 0.f, 0.f, 0.f};

    auto stage = [&](int k0, int bb) {
        __bf16* Al = As + bb * 8192 + w * 8 * 64;
        __bf16* Bl = Bs + bb * 8192 + w * 8 * 64;
        gld16(Ag0 + k0, Al);
        gld16(Ag1 + k0, Al + 2048);
        gld16(Ag2 + k0, Al + 4096);
        gld16(Ag3 + k0, Al + 6144);
        gld16(Bg0 + k0, Bl);
        gld16(Bg1 + k0, Bl + 2048);
        gld16(Bg2 + k0, Bl + 4096);
        gld16(Bg3 + k0, Bl + 6144);
    };

    stage(0, 0);
    __syncthreads();                 // prologue: buf0 ready
    int bb = 0;
    for (int k0 = 0; k0 < K; k0 += 64, bb ^= 1) {
        if (k0 + 64 < K) stage(k0 + 64, bb ^ 1);   // prefetch, in flight
        const __bf16* Ab = As + bb * 8192;
        const __bf16* Bb = Bs + bb * 8192;
        #pragma unroll
        for (int h = 0; h < 2; ++h) {
            const int ch = ((h * 4 + quad) ^ (lrow & 7)) * 8;
            bf16x8 af[4], bf[4];
            #pragma unroll
            for (int rt = 0; rt < 4; ++rt)
                af[rt] = *(const bf16x8*)&Ab[(wr * 64 + rt * 16 + lrow) * 64 + ch];
            #pragma unroll
            for (int ct = 0; ct < 4; ++ct)
                bf[ct] = *(const bf16x8*)&Bb[(wc * 64 + ct * 16 + lrow) * 64 + ch];

            #pragma unroll
            for (int rt = 0; rt < 4; ++rt)
                #pragma unroll
                for (int ct = 0; ct < 4; ++ct)
                    acc[rt][ct] = __builtin_amdgcn_mfma_f32_16x16x32_bf16(
                        af[rt], bf[ct], acc[rt][ct], 0, 0, 0);
        }
        __syncthreads();             // drains prefetch; protects buf reuse
    }

    #pragma unroll
    for (int rt = 0; rt < 4; ++rt)
        #pragma unroll
        for (int ct = 0; ct < 4; ++ct)
            #pragma unroll
            for (int r = 0; r < 4; ++r) {
                const int row = bm + wr * 64 + rt * 16 + quad * 4 + r;
                const int col = bn + wc * 64 + ct * 16 + lrow;
                C[(size_t)row * ldc + col] = (OutT)acc[rt][ct][r];
            }
}

// QKV projection GEMM (bf16 out)
__global__ __launch_bounds__(256) void gemm_qkv(
    const __bf16* __restrict__ A, const __bf16* __restrict__ Bt,
    __bf16* __restrict__ C)
{
    __shared__ __bf16 As[2 * 128 * 64];
    __shared__ __bf16 Bs[2 * 128 * 64];
    gemm_core<__bf16>(A, Bt, C, D_, D_, 0, 3072,
                      blockIdx.y * 128, blockIdx.x * 128, As, Bs);
}

// Merged output projections: balanced 1-D grid of 512: id<256 = enc
// (K=1024), id>=256 = dec (K=512) -> each CU gets one of each (48 K-steps).
__global__ __launch_bounds__(256) void gemm_out(
    const __bf16* __restrict__ A, const __bf16* __restrict__ Woe,
    const __bf16* __restrict__ Wod, float* __restrict__ Cenc,
    float* __restrict__ Cdec)
{
    __shared__ __bf16 As[2 * 128 * 64];
    __shared__ __bf16 Bs[2 * 128 * 64];
    const int id = blockIdx.x;
    if (id < 256) {
        gemm_core<float>(A, Woe, Cenc, 1024, D_, 0, D_,
                         (id >> 3) * 128, (id & 7) * 128, As, Bs);
    } else {
        const int idx = id - 256;
        gemm_core<float>(A, Wod, Cdec, 512, D_, 512, D_,
                         (idx >> 3) * 128, (idx & 7) * 128, As, Bs);
    }
}

// ---------------------------------------------------------------------------
// All 5 weight converts (fp32 W[K][Nn] -> bf16 Wt[Nn][K]) AND the x f32->bf16
// convert in ONE launch.
// grid (16, 16, 13): z<5 = weight transpose-converts (z=4 uses only y<8);
// z in [5,13) = x convert.
// ---------------------------------------------------------------------------
struct WtArgs {
    const float* W[5];
    __bf16*      Wt[5];
    int          K[5];      // rows of W == inner stride of Wt
    int          nyb[5];    // grid-y blocks used
    const float* x;
    __bf16*      xbf;
};

__global__ __launch_bounds__(256) void wt_conv_all(WtArgs ar)
{
    const int z = blockIdx.z;
    if (z >= 5) {
        const int linear = (z - 5) * 256 + blockIdx.y * 16 + blockIdx.x;
        const size_t i = ((size_t)linear * 256 + threadIdx.x) * 8;
        float4 a = *(const float4*)&ar.x[i];
        float4 b = *(const float4*)&ar.x[i + 4];
        bf16x8 o = {(__bf16)a.x, (__bf16)a.y, (__bf16)a.z, (__bf16)a.w,
                    (__bf16)b.x, (__bf16)b.y, (__bf16)b.z, (__bf16)b.w};
        *(bf16x8*)&ar.xbf[i] = o;
        return;
    }
    if (blockIdx.y >= ar.nyb[z]) return;
    const float* W  = ar.W[z];
    __bf16*      Wt = ar.Wt[z];
    const int    K  = ar.K[z];

    __shared__ __bf16 t[64][72];
    const int kb = blockIdx.y * 64;
    const int nb = blockIdx.x * 64;
    {
        const int kl = threadIdx.x >> 2;
        const int c0 = (threadIdx.x & 3) * 16;
        const float* src = W + (size_t)(kb + kl) * D_ + nb + c0;
        #pragma unroll
        for (int u = 0; u < 4; ++u) {
            float4 f = *(const float4*)&src[u * 4];
            t[c0 + u * 4 + 0][kl] = (__bf16)f.x;
            t[c0 + u * 4 + 1][kl] = (__bf16)f.y;
            t[c0 + u * 4 + 2][kl] = (__bf16)f.z;
            t[c0 + u * 4 + 3][kl] = (__bf16)f.w;
        }
    }
    __syncthreads();
    {
        const int nl  = threadIdx.x >> 2;
        const int k0c = (threadIdx.x & 3) * 16;
        __bf16* dst = Wt + (size_t)(nb + nl) * K + kb + k0c;
        *(bf16x8*)&dst[0] = *(const bf16x8*)&t[nl][k0c];
        *(bf16x8*)&dst[8] = *(const bf16x8*)&t[nl][k0c + 8];
    }
}

// ---------------------------------------------------------------------------
// Fused RoPE+RMSNorm (q,k) + V transpose, one launch.
// R15 rope rewrite (old: 16384 blocks, ONE ROW PER WAVE, scalar bf16 loads,
// 64-lane reductions, cross-lane RoPE partner shuffles = Common-mistake #2):
//   blocks [0,2048): q+k path, VECTORIZED. Each lane loads bf16x8 (16B);
//   wave covers 8 rows. RoPE pairs (2p,2p+1) are IN-LANE (cos/sin arrive as
//   one float4 each); RMSNorm reduces over the 8 lanes of a row (3
//   shfl_xor); 16B coalesced stores. Same arithmetic & rounding points.
//   blocks [2048,3072): v-transpose path (unchanged, key-permuted).
// Q is pre-scaled by 0.125*log2e (softmax scale folded in).
// V^T key permutation for IN-REGISTER P (swapped QK^T):
//   pos = quad*8 + hi*4 + lo  <->  key = hi*16 + quad*4 + lo
// ---------------------------------------------------------------------------
__global__ __launch_bounds__(256) void rope_vconv(
    const __bf16* __restrict__ qkv,
    const float* __restrict__ cs, const float* __restrict__ sn,
    __bf16* __restrict__ qbf, __bf16* __restrict__ kbf,
    __bf16* __restrict__ vt)
{
    if (blockIdx.x < 2048) {
        // row id = (b*N + n)*H + h; 32 rows per block, 8 per wave
        const int rid = blockIdx.x * 32 + (threadIdx.x >> 3);
        const int sub = threadIdx.x & 7;          // 8 dims per lane
        const int b = rid >> 15;
        const int n = (rid >> 4) & (N_ - 1);
        const int h = rid & 15;

        const float4 c4 = *(const float4*)&cs[n * (HD_ / 2) + sub * 4];
        const float4 s4 = *(const float4*)&sn[n * (HD_ / 2) + sub * 4];
        const float cc[4] = {c4.x, c4.y, c4.z, c4.w};
        const float ssn[4] = {s4.x, s4.y, s4.z, s4.w};

        const size_t ib = (size_t)(b * N_ + n) * 3072 + h * HD_ + sub * 8;
        const size_t ob = ((size_t)(b * H_ + h) * N_ + n) * HD_ + sub * 8;

        // q (pre-scaled by KSC_)
        {
            bf16x8 v = *(const bf16x8*)&qkv[ib];
            float e[8];
            #pragma unroll
            for (int j = 0; j < 4; ++j) {
                const float re = (float)v[2 * j];
                const float im = (float)v[2 * j + 1];
                e[2 * j]     = re * cc[j] - im * ssn[j];
                e[2 * j + 1] = re * ssn[j] + im * cc[j];
            }
            float ss = 0.f;
            #pragma unroll
            for (int j = 0; j < 8; ++j) ss += e[j] * e[j];
            ss += __shfl_xor(ss, 1, 64);
            ss += __shfl_xor(ss, 2, 64);
            ss += __shfl_xor(ss, 4, 64);
            const float sc = rsqrtf(ss * (1.0f / 64.0f) + EPS_) * KSC_;
            bf16x8 o;
            #pragma unroll
            for (int j = 0; j < 8; ++j) o[j] = (__bf16)(e[j] * sc);
            *(bf16x8*)&qbf[ob] = o;
        }
        // k
        {
            bf16x8 v = *(const bf16x8*)&qkv[ib + 1024];
            float e[8];
            #pragma unroll
            for (int j = 0; j < 4; ++j) {
                const float re = (float)v[2 * j];
                const float im = (float)v[2 * j + 1];
                e[2 * j]     = re * cc[j] - im * ssn[j];
                e[2 * j + 1] = re * ssn[j] + im * cc[j];
            }
            float ss = 0.f;
            #pragma unroll
            for (int j = 0; j < 8; ++j) ss += e[j] * e[j];
            ss += __shfl_xor(ss, 1, 64);
            ss += __shfl_xor(ss, 2, 64);
            ss += __shfl_xor(ss, 4, 64);
            const float sc = rsqrtf(ss * (1.0f / 64.0f) + EPS_);
            bf16x8 o;
            #pragma unroll
            for (int j = 0; j < 8; ++j) o[j] = (__bf16)(e[j] * sc);
            *(bf16x8*)&kbf[ob] = o;
        }
    } else {
        __shared__ __bf16 tile[64][72];
        const int bx = blockIdx.x - 2048;
        const int bh = bx >> 5;
        const int b  = bh >> 4, h = bh & 15;
        const int n0 = (bx & 31) * 64;
        {
            const int nl = threadIdx.x >> 2;
            const int d0 = (threadIdx.x & 3) * 16;
            const __bf16* src =
                qkv + (size_t)(b * N_ + n0 + nl) * 3072 + 2048 + h * HD_ + d0;
            bf16x8 v0 = *(const bf16x8*)&src[0];
            bf16x8 v1 = *(const bf16x8*)&src[8];
            #pragma unroll
            for (int e = 0; e < 8; ++e) {
                tile[d0 + e][nl]     = v0[e];
                tile[d0 + 8 + e][nl] = v1[e];
            }
        }
        __syncthreads();
        {
            const int dl = threadIdx.x >> 2;
            const int nc = (threadIdx.x & 3) * 16;
            __bf16* dst = vt + ((size_t)(bh * HD_ + dl)) * N_ + n0 + nc;
            bf16x8 o0, o1;
            // dst position p holds original key inv(p):
            //   inv(p) = ((p>>2)&1)*16 + ((p>>3)&3)*4 + (p&3)  (within 32-grp)
            #pragma unroll
            for (int e = 0; e < 8; ++e) {
                const int p0 = nc + e;
                const int p1 = nc + 8 + e;
                o0[e] = tile[dl][(p0 & ~31) + (((p0 >> 2) & 1) << 4)
                                 + (((p0 >> 3) & 3) << 2) + (p0 & 3)];
                o1[e] = tile[dl][(p1 & ~31) + (((p1 >> 2) & 1) << 4)
                                 + (((p1 >> 3) & 3) << 2) + (p1 & 3)];
            }
            *(bf16x8*)&dst[0] = o0;
            *(bf16x8*)&dst[8] = o1;
        }
    }
}

// ---------------------------------------------------------------------------
// MFMA flash attention v15 (bf16 in, bf16 out) — UNCHANGED (53.5us floor;
// merged-pass null showed the compiler already interleaves).
// NO setprio (R17/R18 A/B: -23% in our barrier-synced multi-block regime).
// In-register P via swapped QK^T; LDS = K/V only (32.8 KB).
//   K LDS: chunk p = dimchunk*64 + key   (8 dc x 64 keys)
//   V LDS: chunk p = keyoct*64 + dim     (8 ko x 64 dims)  [keys permuted]
// Grid 768 = 3/CU: 256 enc (NG=2) + 512 dec (NG=1, complementary order).
// XCD-keyed: id%8 = head slot (2 enc bh + 2 dec bh per XCD -> 2 MB in L2).
// ---------------------------------------------------------------------------
template <int NG, bool DEC>
__device__ __forceinline__ void attn_core(
    const __bf16* __restrict__ qbase, const __bf16* __restrict__ kbase,
    const __bf16* __restrict__ vbase, __bf16* __restrict__ o,
    int b, int h, int qb, int ntiles,
    __bf16 (*Ks)[4096], __bf16 (*Vs)[4096])
{
    const int tid  = threadIdx.x;
    const int w    = tid >> 6;
    const int lane = tid & 63;
    const int lrow = lane & 15;
    const int quad = lane >> 4;

    // Staging (wave w handles chunk groups m = w and m = w+4):
    //   K group m: lane l -> key l, dims [m*8, m*8+8)
    //   V group m: lane l -> dim l, keypos [m*8, m*8+8)
    const __bf16* kg0 = kbase + (size_t)lane * HD_ + w * 8;        // m=w
    const __bf16* kg1 = kbase + (size_t)lane * HD_ + (w + 4) * 8;  // m=w+4
    const __bf16* vg  = vbase + (size_t)lane * N_;

    // Wave w, group g covers q-rows [i0g, i0g+16)
    int i0g[NG];
    #pragma unroll
    for (int g = 0; g < NG; ++g) i0g[g] = qb * (NG * 64) + g * 64 + w * 16;

    bf16x8 qf[NG][2];
    #pragma unroll
    for (int g = 0; g < NG; ++g)
        #pragma unroll
        for (int kc = 0; kc < 2; ++kc)
            qf[g][kc] = *(const bf16x8*)
                &qbase[(size_t)(i0g[g] + lrow) * HD_ + kc * 32 + quad * 8];

    const f32x4 zero = {0.f, 0.f, 0.f, 0.f};
    f32x4 oacc[NG][4];
    float lsum[NG];
    #pragma unroll
    for (int g = 0; g < NG; ++g) {
        lsum[g] = 0.f;
        #pragma unroll
        for (int c = 0; c < 4; ++c) oacc[g][c] = zero;
    }

    auto stage = [&](int t, int bb) {
        const int j0 = t << 6;
        gld16(kg0 + (size_t)j0 * HD_, &Ks[bb][(w)     * 512]);
        gld16(kg1 + (size_t)j0 * HD_, &Ks[bb][(w + 4) * 512]);
        gld16(vg + j0 + w * 8,        &Vs[bb][(w)     * 512]);
        gld16(vg + j0 + (w + 4) * 8,  &Vs[bb][(w + 4) * 512]);
    };

    stage(0, 0);
    for (int t = 0; t < ntiles; ++t) {
        const int bb = t & 1;
        __syncthreads();            // buf bb staged; prev compute done
        if (t + 1 < ntiles) stage(t + 1, bb ^ 1);

        const int j64 = t << 6;
        // dec: pass 1 (keys [j64+32, j64+64)) entirely above the diagonal
        // for this wave's rows? (wave-uniform -> cheap s_cbranch skip)
        const bool do1 = !DEC || (j64 + 32 <= i0g[0] + 15);

        bf16x8 pf[2][NG];

        // ---- QK + softmax, pass 0 (keys [j64, j64+32)) ----
        {
            bf16x8 kf0 = *(const bf16x8*)&Ks[bb][((quad)     * 64 + lrow) * 8];
            bf16x8 kf1 = *(const bf16x8*)&Ks[bb][((4 + quad) * 64 + lrow) * 8];
            bf16x8 kf2 = *(const bf16x8*)&Ks[bb][((quad)     * 64 + 16 + lrow) * 8];
            bf16x8 kf3 = *(const bf16x8*)&Ks[bb][((4 + quad) * 64 + 16 + lrow) * 8];

            f32x4 s0[NG], s1[NG];
            #pragma unroll
            for (int g = 0; g < NG; ++g) { s0[g] = zero; s1[g] = zero; }
            #pragma unroll
            for (int g = 0; g < NG; ++g)
                s0[g] = __builtin_amdgcn_mfma_f32_16x16x32_bf16(kf0, qf[g][0], s0[g], 0, 0, 0);
            #pragma unroll
            for (int g = 0; g < NG; ++g)
                s0[g] = __builtin_amdgcn_mfma_f32_16x16x32_bf16(kf1, qf[g][1], s0[g], 0, 0, 0);
            #pragma unroll
            for (int g = 0; g < NG; ++g)
                s1[g] = __builtin_amdgcn_mfma_f32_16x16x32_bf16(kf2, qf[g][0], s1[g], 0, 0, 0);
            #pragma unroll
            for (int g = 0; g < NG; ++g)
                s1[g] = __builtin_amdgcn_mfma_f32_16x16x32_bf16(kf3, qf[g][1], s1[g], 0, 0, 0);

            #pragma unroll
            for (int g = 0; g < NG; ++g) {
                float pA[4], pB[4];
                if (DEC && (j64 + 31 > i0g[g])) {   // pass reaches diagonal
                    const int i = i0g[g] + lrow;
                    #pragma unroll
                    for (int r = 0; r < 4; ++r) {
                        const int k0 = j64 + quad * 4 + r;
                        pA[r] = (k0      <= i) ? EXP2F(s0[g][r]) : 0.f;
                        pB[r] = (k0 + 16 <= i) ? EXP2F(s1[g][r]) : 0.f;
                    }
                } else {
                    #pragma unroll
                    for (int r = 0; r < 4; ++r) {
                        pA[r] = EXP2F(s0[g][r]);
                        pB[r] = EXP2F(s1[g][r]);
                    }
                }
                lsum[g] += (pA[0] + pA[1]) + (pA[2] + pA[3])
                         + (pB[0] + pB[1]) + (pB[2] + pB[3]);
                pf[0][g] = (bf16x8){(__bf16)pA[0], (__bf16)pA[1],
                                    (__bf16)pA[2], (__bf16)pA[3],
                                    (__bf16)pB[0], (__bf16)pB[1],
                                    (__bf16)pB[2], (__bf16)pB[3]};
            }
        }

        // ---- QK + softmax, pass 1 (keys [j64+32, j64+64)) ----
        if (do1) {
            bf16x8 kf0 = *(const bf16x8*)&Ks[bb][((quad)     * 64 + 32 + lrow) * 8];
            bf16x8 kf1 = *(const bf16x8*)&Ks[bb][((4 + quad) * 64 + 32 + lrow) * 8];
            bf16x8 kf2 = *(const bf16x8*)&Ks[bb][((quad)     * 64 + 48 + lrow) * 8];
            bf16x8 kf3 = *(const bf16x8*)&Ks[bb][((4 + quad) * 64 + 48 + lrow) * 8];

            f32x4 s0[NG], s1[NG];
            #pragma unroll
            for (int g = 0; g < NG; ++g) { s0[g] = zero; s1[g] = zero; }
            #pragma unroll
            for (int g = 0; g < NG; ++g)
                s0[g] = __builtin_amdgcn_mfma_f32_16x16x32_bf16(kf0, qf[g][0], s0[g], 0, 0, 0);
            #pragma unroll
            for (int g = 0; g < NG; ++g)
                s0[g] = __builtin_amdgcn_mfma_f32_16x16x32_bf16(kf1, qf[g][1], s0[g], 0, 0, 0);
            #pragma unroll
            for (int g = 0; g < NG; ++g)
                s1[g] = __builtin_amdgcn_mfma_f32_16x16x32_bf16(kf2, qf[g][0], s1[g], 0, 0, 0);
            #pragma unroll
            for (int g = 0; g < NG; ++g)
                s1[g] = __builtin_amdgcn_mfma_f32_16x16x32_bf16(kf3, qf[g][1], s1[g], 0, 0, 0);

            const int jp = j64 + 32;
            #pragma unroll
            for (int g = 0; g < NG; ++g) {
                float pA[4], pB[4];
                if (DEC && (jp + 31 > i0g[g])) {   // pass reaches diagonal
                    const int i = i0g[g] + lrow;
                    #pragma unroll
                    for (int r = 0; r < 4; ++r) {
                        const int k0 = jp + quad * 4 + r;
                        pA[r] = (k0      <= i) ? EXP2F(s0[g][r]) : 0.f;
                        pB[r] = (k0 + 16 <= i) ? EXP2F(s1[g][r]) : 0.f;
                    }
                } else {
                    #pragma unroll
                    for (int r = 0; r < 4; ++r) {
                        pA[r] = EXP2F(s0[g][r]);
                        pB[r] = EXP2F(s1[g][r]);
                    }
                }
                lsum[g] += (pA[0] + pA[1]) + (pA[2] + pA[3])
                         + (pB[0] + pB[1]) + (pB[2] + pB[3]);
                pf[1][g] = (bf16x8){(__bf16)pA[0], (__bf16)pA[1],
                                    (__bf16)pA[2], (__bf16)pA[3],
                                    (__bf16)pB[0], (__bf16)pB[1],
                                    (__bf16)pB[2], (__bf16)pB[3]};
            }
        }

        // ---- PV, pass 0 ----
        {
            bf16x8 vf0 = *(const bf16x8*)&Vs[bb][((quad) * 64 +  0 + lrow) * 8];
            bf16x8 vf1 = *(const bf16x8*)&Vs[bb][((quad) * 64 + 16 + lrow) * 8];
            bf16x8 vf2 = *(const bf16x8*)&Vs[bb][((quad) * 64 + 32 + lrow) * 8];
            bf16x8 vf3 = *(const bf16x8*)&Vs[bb][((quad) * 64 + 48 + lrow) * 8];
            #pragma unroll
            for (int g = 0; g < NG; ++g) {
                oacc[g][0] = __builtin_amdgcn_mfma_f32_16x16x32_bf16(pf[0][g], vf0, oacc[g][0], 0, 0, 0);
                oacc[g][1] = __builtin_amdgcn_mfma_f32_16x16x32_bf16(pf[0][g], vf1, oacc[g][1], 0, 0, 0);
                oacc[g][2] = __builtin_amdgcn_mfma_f32_16x16x32_bf16(pf[0][g], vf2, oacc[g][2], 0, 0, 0);
                oacc[g][3] = __builtin_amdgcn_mfma_f32_16x16x32_bf16(pf[0][g], vf3, oacc[g][3], 0, 0, 0);
            }
        }

        // ---- PV, pass 1 ----
        if (do1) {
            bf16x8 vf0 = *(const bf16x8*)&Vs[bb][((4 + quad) * 64 +  0 + lrow) * 8];
            bf16x8 vf1 = *(const bf16x8*)&Vs[bb][((4 + quad) * 64 + 16 + lrow) * 8];
            bf16x8 vf2 = *(const bf16x8*)&Vs[bb][((4 + quad) * 64 + 32 + lrow) * 8];
            bf16x8 vf3 = *(const bf16x8*)&Vs[bb][((4 + quad) * 64 + 48 + lrow) * 8];
            #pragma unroll
            for (int g = 0; g < NG; ++g) {
                oacc[g][0] = __builtin_amdgcn_mfma_f32_16x16x32_bf16(pf[1][g], vf0, oacc[g][0], 0, 0, 0);
                oacc[g][1] = __builtin_amdgcn_mfma_f32_16x16x32_bf16(pf[1][g], vf1, oacc[g][1], 0, 0, 0);
                oacc[g][2] = __builtin_amdgcn_mfma_f32_16x16x32_bf16(pf[1][g], vf2, oacc[g][2], 0, 0, 0);
                oacc[g][3] = __builtin_amdgcn_mfma_f32_16x16x32_bf16(pf[1][g], vf3, oacc[g][3], 0, 0, 0);
            }
        }
    }

    // Row sums: lane holds partial for q=lrow over its quad's keys.
    // Combine quads (lanes lrow, 16+lrow, 32+lrow, 48+lrow), then gather
    // the recip for q = quad*4+r from lane (quad*4+r).
    float lrec[NG][4];
    #pragma unroll
    for (int g = 0; g < NG; ++g) {
        float s = lsum[g];
        s += __shfl_xor(s, 16, 64);
        s += __shfl_xor(s, 32, 64);
        s = 1.0f / s;
        #pragma unroll
        for (int r = 0; r < 4; ++r)
            lrec[g][r] = __shfl(s, quad * 4 + r, 64);
    }

    // O (bf16, [4096][1024], col = h*64 + dim); C-layout row=q=quad*4+r
    #pragma unroll
    for (int g = 0; g < NG; ++g)
        #pragma unroll
        for (int c = 0; c < 4; ++c)
            #pragma unroll
            for (int r = 0; r < 4; ++r) {
                const int i = i0g[g] + quad * 4 + r;
                o[(size_t)(b * N_ + i) * D_ + h * HD_ + c * 16 + lrow] =
                    (__bf16)(oacc[g][c][r] * lrec[g][r]);
            }
}

__global__ __launch_bounds__(256) void attn_mfma(
    const __bf16* __restrict__ qbf, const __bf16* __restrict__ kbf,
    const __bf16* __restrict__ vtbf, __bf16* __restrict__ o)
{
    __shared__ __bf16 Ks[2][4096];       // 8 KB per buffer
    __shared__ __bf16 Vs[2][4096];

    if (blockIdx.x < 256) {
        // enc: id = qb*16 + e  (XCD = e%8); 128-row blocks, NG=2
        const int e  = blockIdx.x & 15;
        const int bh = (e >> 3) * 16 + (e & 7);
        const int qb = blockIdx.x >> 4;          // 0..15
        attn_core<2, false>(
            qbf  + (size_t)bh * N_ * HD_, kbf + (size_t)bh * N_ * HD_,
            vtbf + (size_t)bh * HD_ * N_, o,
            bh >> 4, bh & 15, qb, N_ >> 6, Ks, Vs);
    } else {
        // dec: id = 256 + p*16 + d (XCD = d%8); 64-row blocks.
        // Complementary qb order (p<16 -> 31-p heavy, else p-16): the two
        // dec blocks landing on one CU sum to 33 tiles; per-CU makespan is
        // governed by the 32-tile enc block either way.
        const int idx = blockIdx.x - 256;
        const int d   = idx & 15;
        const int bh  = (d >> 3) * 16 + 8 + (d & 7);
        const int p   = idx >> 4;                // 0..31
        const int qb  = (p < 16) ? (31 - p) : (p - 16);
        attn_core<1, true>(
            qbf  + (size_t)bh * N_ * HD_, kbf + (size_t)bh * N_ * HD_,
            vtbf + (size_t)bh * HD_ * N_, o,
            bh >> 4, bh & 15, qb, qb + 1, Ks, Vs);
    }
}

// ---------------------------------------------------------------------------
extern "C" void kernel_launch(void* const* d_in, const int* in_sizes, int n_in,
                              void* d_out, int out_size, void* d_ws, size_t ws_size,
                              hipStream_t stream)
{
    const float* x   = (const float*)d_in[0];
    const float* cs  = (const float*)d_in[1];
    const float* sn  = (const float*)d_in[2];
    const float* Wq  = (const float*)d_in[3];
    const float* Wk  = (const float*)d_in[4];
    const float* Wv  = (const float*)d_in[5];
    const float* Woe = (const float*)d_in[6];
    const float* Wod = (const float*)d_in[7];

    float* enc_out = (float*)d_out;
    float* dec_out = enc_out + (size_t)M_ * D_;

    // Workspace (57 MB), stream-ordered aliasing:
    //   [0,8)    xbf      -> reused as vtbf after QKV GEMM
    //   [8,14)   wqkv_t   (3072 x 1024 bf16)
    //   [14,16)  woe_t    (1024 x 1024 bf16)
    //   [16,17)  wod_t    (1024 x 512 bf16)
    //   [17,41)  qkv      (4096 x 3072 bf16) -> reused as obuf
    //   [41,49)  qbf head-major
    //   [49,57)  kbf head-major
    char* ws = (char*)d_ws;
    __bf16* xbf    = (__bf16*)(ws);
    __bf16* wqkv_t = (__bf16*)(ws + MB(8));
    __bf16* woe_t  = (__bf16*)(ws + MB(14));
    __bf16* wod_t  = (__bf16*)(ws + MB(16));
    __bf16* qkv    = (__bf16*)(ws + MB(17));
    __bf16* qbf    = (__bf16*)(ws + MB(41));
    __bf16* kbf    = (__bf16*)(ws + MB(49));
    __bf16* vtbf   = xbf;     // xbf dead after QKV GEMM
    __bf16* obuf   = qkv;     // qkv dead after rope_vconv

    // All weight converts + x convert in one launch
    WtArgs wa;
    wa.W[0] = Wq;  wa.Wt[0] = wqkv_t;                 wa.K[0] = 1024; wa.nyb[0] = 16;
    wa.W[1] = Wk;  wa.Wt[1] = wqkv_t + 1024 * 1024;   wa.K[1] = 1024; wa.nyb[1] = 16;
    wa.W[2] = Wv;  wa.Wt[2] = wqkv_t + 2048 * 1024;   wa.K[2] = 1024; wa.nyb[2] = 16;
    wa.W[3] = Woe; wa.Wt[3] = woe_t;                  wa.K[3] = 1024; wa.nyb[3] = 16;
    wa.W[4] = Wod; wa.Wt[4] = wod_t;                  wa.K[4] = 512;  wa.nyb[4] = 8;
    wa.x = x; wa.xbf = xbf;
    wt_conv_all<<<dim3(16, 16, 13), 256, 0, stream>>>(wa);

    // Fused QKV projection (bf16 out)
    gemm_qkv<<<dim3(3072 / 128, M_ / 128), 256, 0, stream>>>(xbf, wqkv_t, qkv);

    // RoPE+RMSNorm (vectorized) + V transpose (key-permuted), one launch
    rope_vconv<<<2048 + 1024, 256, 0, stream>>>(qkv, cs, sn, qbf, kbf, vtbf);

    // Attention: 768 blocks = 3/CU (256 enc NG=2 + 512 dec complementary)
    attn_mfma<<<dim3(768), 256, 0, stream>>>(qbf, kbf, vtbf, obuf);

    // Merged output projections (fp32 out), balanced 1-D grid
    gemm_out<<<dim3(512), 256, 0, stream>>>(
        obuf, woe_t, wod_t, enc_out, dec_out);
}